// Round 5
// baseline (152.113 us; speedup 1.0000x reference)
//
#include <hip/hip_runtime.h>
#include <math.h>

#define BB  16
#define TT  12
#define T2C 10
#define NN  300
#define DD  64
#define M3  900   // 3*NN
#define NW  (BB*T2C)

typedef _Float16 f16;
typedef __attribute__((ext_vector_type(8)))  _Float16 f16x8;
typedef __attribute__((ext_vector_type(16))) float    f32x16;

#define KS 72   // fp16 row stride (144 B): 4-way (free-ish) instead of 8-way conflicts

static __device__ inline unsigned pk2(f16 a, f16 b) {
    union { f16 h[2]; unsigned u; } x; x.h[0] = a; x.h[1] = b; return x.u;
}

// ---------------------------------------------------------------------------
// k_prep: blk < 960: fused norm + per-timestep ksum basis (as round 4).
//         blk == 960: transpose w1/w2 into MFMA A-fragment order (fp16),
//         so k_ffn lanes load their fragments with coalesced b128 reads.
// ---------------------------------------------------------------------------
__global__ __launch_bounds__(256) void k_prep(const float* __restrict__ feat,
                                              const float* __restrict__ weights,
                                              const float* __restrict__ w1,
                                              const float* __restrict__ w2,
                                              float* __restrict__ sigw,
                                              float* __restrict__ invn,
                                              float* __restrict__ tsum,
                                              f16* __restrict__ w1f,
                                              f16* __restrict__ w2f) {
    __shared__ float part[4][DD];
    int blk = blockIdx.x;
    int tid = threadIdx.x;

    if (blk == BB * TT * 5) {
        // frag layout: [mat][loc=ct*4+ks][lane][8]; elem j = w[d*64+hcol],
        // d = ks*16 + 8*(lane>>5) + j, hcol = ct*32 + (lane&31)
        for (int p = tid; p < 1024; p += 256) {
            int lane = p & 63, s = p >> 6;
            int mat = s >> 3, loc = s & 7, ct = loc >> 2, ks = loc & 3;
            int hcol = ct * 32 + (lane & 31);
            const float* w = mat ? w2 : w1;
            f16* dst = (mat ? w2f : w1f) + ((size_t)loc * 64 + lane) * 8;
            f16x8 v;
            #pragma unroll
            for (int j = 0; j < 8; j++) {
                int d = ks * 16 + 8 * (lane >> 5) + j;
                v[j] = (f16)w[d * DD + hcol];
            }
            *(f16x8*)dst = v;
        }
        return;
    }

    int bt = blk / 5, ch = blk % 5;
    int row0 = bt * NN + ch * 60;
    int d = tid & 63, w = tid >> 6;

    float sg = 1.0f / (1.0f + expf(-weights[d]));
    if (blk == 0 && tid < 64) sigw[d] = sg;

    float acc = 0.f;
    for (int i = w; i < 60; i += 4) {
        int gr = row0 + i;
        float f = feat[(size_t)gr * DD + d];
        float x = f * sg;
        float ss = x * x;
        #pragma unroll
        for (int off = 32; off > 0; off >>= 1) ss += __shfl_xor(ss, off, 64);
        float in = 1.0f / fmaxf(sqrtf(ss), 1e-12f);
        if (d == 0) invn[gr] = in;
        acc += f * in;
    }
    part[w][d] = acc;
    __syncthreads();
    if (w == 0) {
        float v = (part[0][d] + part[1][d] + part[2][d] + part[3][d]) * sg;
        atomicAdd(&tsum[(size_t)bt * DD + d], v);
    }
}

// ---------------------------------------------------------------------------
// k_agg v2: invn folded into Vt, sigw^2 into Q'' -> only the RAW feat tile
// staged (Ft [m][d], Vt [d][m]*invn). Per kt: reg-prefetch next tile, each
// wave computes full S^T for its n-block (8 MFMA) into a PRIVATE LDS region
// (same-wave round trip: no barrier), phase2 (4 MFMA), then 2 barriers
// around the staging write. deg via fp32 tsum basis as before.
// ---------------------------------------------------------------------------
__global__ __launch_bounds__(256) void k_agg(const float* __restrict__ feat,
                                             const float* __restrict__ sigw,
                                             const float* __restrict__ invn,
                                             const float* __restrict__ tsum,
                                             float* __restrict__ agg) {
    __shared__ f16 Ft[64 * KS];        // raw feat tile [m][d]
    __shared__ f16 Vt[64 * KS];        // feat*invn transposed [d][m]
    __shared__ f16 Sw[4][32 * KS];     // per-wave S [n_local][m]
    __shared__ float degp[64][4];
    __shared__ float degs[64];

    int blk = blockIdx.x;
    int rb = blk % 5, wdw = blk / 5;
    int t2 = wdw % T2C, b = wdw / T2C;
    int n0 = rb * 64;
    int qrow0 = (b * TT + t2 + 2) * NN;
    int krow0 = (b * TT + t2) * NN;
    int tid = threadIdx.x;
    int wv = tid >> 6, lane = tid & 63;
    int l31 = lane & 31, lh = lane >> 5;
    int nt = wv & 1;    // n-block of this wave
    int dt = wv >> 1;   // d-block of this wave (phase2 / output)

    // ---- deg partials: deg[n] = (feat[n]*sigw . ksum_w) * invn[n] ----
    {
        int r = tid >> 2, qd = (tid & 3) * 16;
        float p = 0.f;
        if (n0 + r < NN) {
            int gr = qrow0 + n0 + r;
            float in = invn[gr];
            const float4* f4 = (const float4*)(feat + (size_t)gr * DD + qd);
            const float4* s4 = (const float4*)(sigw + qd);
            const float4* t4 = (const float4*)(tsum + (size_t)(b * TT + t2) * DD + qd);
            #pragma unroll
            for (int i = 0; i < 4; i++) {
                float4 f = f4[i], s = s4[i];
                float4 k0 = t4[i], k1 = t4[i + 16], k2 = t4[i + 32];
                p += f.x * s.x * (k0.x + k1.x + k2.x) + f.y * s.y * (k0.y + k1.y + k2.y)
                   + f.z * s.z * (k0.z + k1.z + k2.z) + f.w * s.w * (k0.w + k1.w + k2.w);
            }
            p *= in;
        }
        degp[r][tid & 3] = p;
    }

    // ---- Q'' B-frags in registers: feat_q * sigw^2 * invn_q ----
    f16x8 qf[4];
    {
        int nloc = n0 + nt * 32 + l31;
        bool ok = nloc < NN;
        int gr = qrow0 + nloc;
        float in = ok ? invn[gr] : 0.f;
        #pragma unroll
        for (int ks = 0; ks < 4; ks++) {
            int c0 = ks * 16 + 8 * lh;
            f16x8 qv;
            #pragma unroll
            for (int i = 0; i < 8; i++) qv[i] = (f16)0.f;
            if (ok) {
                float4 f0 = *(const float4*)(feat + (size_t)gr * DD + c0);
                float4 f1 = *(const float4*)(feat + (size_t)gr * DD + c0 + 4);
                float4 s0 = *(const float4*)(sigw + c0);
                float4 s1 = *(const float4*)(sigw + c0 + 4);
                qv[0] = (f16)(f0.x * s0.x * s0.x * in); qv[1] = (f16)(f0.y * s0.y * s0.y * in);
                qv[2] = (f16)(f0.z * s0.z * s0.z * in); qv[3] = (f16)(f0.w * s0.w * s0.w * in);
                qv[4] = (f16)(f1.x * s1.x * s1.x * in); qv[5] = (f16)(f1.y * s1.y * s1.y * in);
                qv[6] = (f16)(f1.z * s1.z * s1.z * in); qv[7] = (f16)(f1.w * s1.w * s1.w * in);
            }
            qf[ks] = qv;
        }
    }

    // ---- staging thread mapping: 2 m-rows, 8 d-cols per thread ----
    int mr = (tid & 31) * 2;
    int db = (tid >> 5) * 8;

    float4 A0, A1, B0, B1;
    float i0, i1;
    // prologue: tile 0 (m 0..63 always valid)
    {
        int g0 = krow0 + mr;
        A0 = *(const float4*)(feat + (size_t)g0 * DD + db);
        A1 = *(const float4*)(feat + (size_t)g0 * DD + db + 4);
        B0 = *(const float4*)(feat + (size_t)(g0 + 1) * DD + db);
        B1 = *(const float4*)(feat + (size_t)(g0 + 1) * DD + db + 4);
        i0 = invn[g0]; i1 = invn[g0 + 1];
    }
    {
        f16x8 r0, r1;
        r0[0]=(f16)A0.x; r0[1]=(f16)A0.y; r0[2]=(f16)A0.z; r0[3]=(f16)A0.w;
        r0[4]=(f16)A1.x; r0[5]=(f16)A1.y; r0[6]=(f16)A1.z; r0[7]=(f16)A1.w;
        r1[0]=(f16)B0.x; r1[1]=(f16)B0.y; r1[2]=(f16)B0.z; r1[3]=(f16)B0.w;
        r1[4]=(f16)B1.x; r1[5]=(f16)B1.y; r1[6]=(f16)B1.z; r1[7]=(f16)B1.w;
        *(f16x8*)&Ft[mr * KS + db] = r0;
        *(f16x8*)&Ft[(mr + 1) * KS + db] = r1;
        float a[8] = {A0.x, A0.y, A0.z, A0.w, A1.x, A1.y, A1.z, A1.w};
        float c[8] = {B0.x, B0.y, B0.z, B0.w, B1.x, B1.y, B1.z, B1.w};
        #pragma unroll
        for (int i = 0; i < 8; i++)
            *(unsigned*)&Vt[(db + i) * KS + mr] = pk2((f16)(a[i] * i0), (f16)(c[i] * i1));
    }
    __syncthreads();
    if (tid < 64)
        degs[tid] = degp[tid][0] + degp[tid][1] + degp[tid][2] + degp[tid][3];

    f32x16 acc;
    #pragma unroll
    for (int i = 0; i < 16; i++) acc[i] = 0.f;

    f16* sl = &Sw[wv][0];

    for (int kt = 0; kt < 15; kt++) {
        bool has_next = kt < 14;
        // ---- issue prefetch loads for kt+1 (consumed after the barrier) ----
        if (has_next) {
            int m0n = (kt + 1) * 64;
            int gm0 = m0n + mr, gm1 = gm0 + 1;
            bool ok0 = gm0 < M3, ok1 = gm1 < M3;
            int g0 = krow0 + (ok0 ? gm0 : 0);
            int g1 = krow0 + (ok1 ? gm1 : 0);
            A0 = *(const float4*)(feat + (size_t)g0 * DD + db);
            A1 = *(const float4*)(feat + (size_t)g0 * DD + db + 4);
            B0 = *(const float4*)(feat + (size_t)g1 * DD + db);
            B1 = *(const float4*)(feat + (size_t)g1 * DD + db + 4);
            i0 = ok0 ? invn[g0] : 0.f;
            i1 = ok1 ? invn[g1] : 0.f;
        }

        // ---- phase1: full S^T for this wave's n-block (both m-halves) ----
        f32x16 c1a, c1b;
        #pragma unroll
        for (int i = 0; i < 16; i++) { c1a[i] = 0.f; c1b[i] = 0.f; }
        #pragma unroll
        for (int ks = 0; ks < 4; ks++) {
            f16x8 af0 = *(const f16x8*)&Ft[(l31) * KS + ks * 16 + 8 * lh];
            f16x8 af1 = *(const f16x8*)&Ft[(32 + l31) * KS + ks * 16 + 8 * lh];
            c1a = __builtin_amdgcn_mfma_f32_32x32x16_f16(af0, qf[ks], c1a, 0, 0, 0);
            c1b = __builtin_amdgcn_mfma_f32_32x32x16_f16(af1, qf[ks], c1b, 0, 0, 0);
        }
        // pack S rows into this wave's private region [n_local=l31][m]
        #pragma unroll
        for (int g = 0; g < 4; g++) {
            union { f16 h[4]; uint2 u; } pa, pb;
            pa.h[0] = (f16)c1a[4*g+0]; pa.h[1] = (f16)c1a[4*g+1];
            pa.h[2] = (f16)c1a[4*g+2]; pa.h[3] = (f16)c1a[4*g+3];
            pb.h[0] = (f16)c1b[4*g+0]; pb.h[1] = (f16)c1b[4*g+1];
            pb.h[2] = (f16)c1b[4*g+2]; pb.h[3] = (f16)c1b[4*g+3];
            *(uint2*)&sl[l31 * KS + 8 * g + 4 * lh]      = pa.u;
            *(uint2*)&sl[l31 * KS + 32 + 8 * g + 4 * lh] = pb.u;
        }
        // ---- phase2: acc(nt, dt) += S . (invn*V)  (same-wave LDS reuse) ----
        #pragma unroll
        for (int ms = 0; ms < 4; ms++) {
            f16x8 sa = *(const f16x8*)&sl[l31 * KS + ms * 16 + 8 * lh];
            f16x8 vb = *(const f16x8*)&Vt[(dt * 32 + l31) * KS + ms * 16 + 8 * lh];
            acc = __builtin_amdgcn_mfma_f32_32x32x16_f16(sa, vb, acc, 0, 0, 0);
        }
        __syncthreads();   // everyone done reading Ft/Vt
        if (has_next) {
            f16x8 r0, r1;
            r0[0]=(f16)A0.x; r0[1]=(f16)A0.y; r0[2]=(f16)A0.z; r0[3]=(f16)A0.w;
            r0[4]=(f16)A1.x; r0[5]=(f16)A1.y; r0[6]=(f16)A1.z; r0[7]=(f16)A1.w;
            r1[0]=(f16)B0.x; r1[1]=(f16)B0.y; r1[2]=(f16)B0.z; r1[3]=(f16)B0.w;
            r1[4]=(f16)B1.x; r1[5]=(f16)B1.y; r1[6]=(f16)B1.z; r1[7]=(f16)B1.w;
            *(f16x8*)&Ft[mr * KS + db] = r0;
            *(f16x8*)&Ft[(mr + 1) * KS + db] = r1;
            float a[8] = {A0.x, A0.y, A0.z, A0.w, A1.x, A1.y, A1.z, A1.w};
            float c[8] = {B0.x, B0.y, B0.z, B0.w, B1.x, B1.y, B1.z, B1.w};
            #pragma unroll
            for (int i = 0; i < 8; i++)
                *(unsigned*)&Vt[(db + i) * KS + mr] = pk2((f16)(a[i] * i0), (f16)(c[i] * i1));
        }
        __syncthreads();   // next tile staged
    }

    float* ob = agg + (size_t)(b * T2C + t2) * NN * DD;
    int dcol = dt * 32 + l31;
    #pragma unroll
    for (int g = 0; g < 4; g++) {
        #pragma unroll
        for (int i = 0; i < 4; i++) {
            int rl = nt * 32 + 8 * g + 4 * lh + i;
            int n = n0 + rl;
            if (n < NN) {
                float dg = degs[rl];
                float dinv = (dg == 0.f) ? 0.f : 1.f / dg;
                ob[(size_t)n * DD + dcol] = acc[4 * g + i] * dinv;
            }
        }
    }
}

// ---------------------------------------------------------------------------
// k_ffn v2: weights come pre-transposed as fp16 A-fragments from global
// (L2-resident, loaded at kernel entry -> fully hidden). Per-row pow2
// scaling as round 4. Barrier count 4; no W staging VALU.
// ---------------------------------------------------------------------------
__global__ __launch_bounds__(256) void k_ffn(const float* __restrict__ aggin,
                                             const float* __restrict__ feat,
                                             const f16* __restrict__ w1f,
                                             const f16* __restrict__ w2f,
                                             const float* __restrict__ b1,
                                             const float* __restrict__ b2,
                                             const float* __restrict__ gamma,
                                             const float* __restrict__ beta,
                                             float* __restrict__ out) {
    __shared__ f16 Al[64 * KS];
    __shared__ f16 Hl[64 * KS];
    __shared__ float Ol[64 * 68];
    __shared__ float red[64][4][2];
    __shared__ float rmax[64][4];
    __shared__ float scls[64];
    __shared__ float isls[64];

    int tid = threadIdx.x;
    int wv = tid >> 6, lane = tid & 63;
    int l31 = lane & 31, lh = lane >> 5;
    int row0 = blockIdx.x * 64;
    int r = tid >> 2, q = tid & 3, c0 = q * 16;
    int ct = wv & 1, rt = wv >> 1;

    // ---- prefetch weight A-frags (coalesced b128, L2-hot) ----
    f16x8 w1a[4], w2a[4];
    #pragma unroll
    for (int ks = 0; ks < 4; ks++) {
        w1a[ks] = *(const f16x8*)(w1f + ((size_t)(ct * 4 + ks) * 64 + lane) * 8);
        w2a[ks] = *(const f16x8*)(w2f + ((size_t)(ct * 4 + ks) * 64 + lane) * 8);
    }

    // ---- read agg fp32, per-row absmax ----
    float av[16];
    {
        const float4* src = (const float4*)(aggin + (size_t)(row0 + r) * DD + c0);
        float mx = 0.f;
        #pragma unroll
        for (int i = 0; i < 4; i++) {
            float4 f = src[i];
            av[4*i+0] = f.x; av[4*i+1] = f.y; av[4*i+2] = f.z; av[4*i+3] = f.w;
            mx = fmaxf(mx, fmaxf(fmaxf(fabsf(f.x), fabsf(f.y)),
                                 fmaxf(fabsf(f.z), fabsf(f.w))));
        }
        rmax[r][q] = mx;
    }
    __syncthreads();

    // ---- per-row pow2 scale; stage A_s fp16 ----
    {
        float rm = fmaxf(fmaxf(rmax[r][0], rmax[r][1]), fmaxf(rmax[r][2], rmax[r][3]));
        int e = 0;
        frexpf(rm, &e);
        float scl = (rm > 1.f) ? exp2f((float)-e) : 1.f;
        if (q == 0) { scls[r] = scl; isls[r] = (rm > 1.f) ? exp2f((float)e) : 1.f; }
        #pragma unroll
        for (int i = 0; i < 2; i++) {
            f16x8 v;
            #pragma unroll
            for (int j = 0; j < 8; j++) v[j] = (f16)(av[8 * i + j] * scl);
            *(f16x8*)&Al[r * KS + c0 + 8 * i] = v;
        }
    }
    __syncthreads();

    // phase A: h_s^T tile = w1^T . A_s^T
    f32x16 hc;
    #pragma unroll
    for (int i = 0; i < 16; i++) hc[i] = 0.f;
    #pragma unroll
    for (int ks = 0; ks < 4; ks++) {
        f16x8 bf = *(const f16x8*)&Al[(rt * 32 + l31) * KS + ks * 16 + 8 * lh];
        hc = __builtin_amdgcn_mfma_f32_32x32x16_f16(w1a[ks], bf, hc, 0, 0, 0);
    }
    {
        float sA = scls[rt * 32 + l31];
        #pragma unroll
        for (int g = 0; g < 4; g++) {
            union { f16 h[4]; uint2 u; } p;
            #pragma unroll
            for (int i = 0; i < 4; i++) {
                int hcol = ct * 32 + 8 * g + 4 * lh + i;
                p.h[i] = (f16)fmaxf(hc[4 * g + i] + sA * b1[hcol], 0.f);
            }
            *(uint2*)&Hl[(rt * 32 + l31) * KS + ct * 32 + 8 * g + 4 * lh] = p.u;
        }
    }
    __syncthreads();

    // phase B: o_s^T tile = w2^T . h_s^T
    f32x16 oc;
    #pragma unroll
    for (int i = 0; i < 16; i++) oc[i] = 0.f;
    #pragma unroll
    for (int ks = 0; ks < 4; ks++) {
        f16x8 bf = *(const f16x8*)&Hl[(rt * 32 + l31) * KS + ks * 16 + 8 * lh];
        oc = __builtin_amdgcn_mfma_f32_32x32x16_f16(w2a[ks], bf, oc, 0, 0, 0);
    }
    #pragma unroll
    for (int g = 0; g < 4; g++) {
        float4 o4 = make_float4(oc[4*g+0], oc[4*g+1], oc[4*g+2], oc[4*g+3]);
        *(float4*)&Ol[(rt * 32 + l31) * 68 + ct * 32 + 8 * g + 4 * lh] = o4;
    }
    __syncthreads();

    // epilogue: s = o_s/s_n + b2 + residual; LayerNorm
    size_t grow = row0 + r;
    int n = (int)(grow % NN);
    int bt = (int)(grow / NN);
    int t2 = bt % T2C, bb = bt / T2C;
    size_t frow = (size_t)(bb * TT + t2 + 2) * NN + n;
    float is = isls[r];
    float v[16];
    float sum = 0.f;
    #pragma unroll
    for (int i = 0; i < 16; i++) {
        int c = c0 + i;
        float x = Ol[r * 68 + c] * is + b2[c] + feat[frow * DD + c];
        v[i] = x; sum += x;
    }
    red[r][q][0] = sum;
    __syncthreads();
    float mu = (red[r][0][0] + red[r][1][0] + red[r][2][0] + red[r][3][0]) * (1.f / 64.f);
    float s2 = 0.f;
    #pragma unroll
    for (int i = 0; i < 16; i++) { float d = v[i] - mu; s2 += d * d; }
    red[r][q][1] = s2;
    __syncthreads();
    float var = (red[r][0][1] + red[r][1][1] + red[r][2][1] + red[r][3][1]) * (1.f / 64.f);
    float rs = rsqrtf(var + 1e-5f);
    #pragma unroll
    for (int i4 = 0; i4 < 4; i4++) {
        int c = c0 + 4 * i4;
        float4 g4 = *(const float4*)(gamma + c);
        float4 be = *(const float4*)(beta + c);
        float4 o4;
        o4.x = (v[4*i4+0] - mu) * rs * g4.x + be.x;
        o4.y = (v[4*i4+1] - mu) * rs * g4.y + be.y;
        o4.z = (v[4*i4+2] - mu) * rs * g4.z + be.z;
        o4.w = (v[4*i4+3] - mu) * rs * g4.w + be.w;
        *(float4*)(out + grow * DD + c) = o4;
    }
}

// ---------------------------------------------------------------------------
extern "C" void kernel_launch(void* const* d_in, const int* in_sizes, int n_in,
                              void* d_out, int out_size, void* d_ws, size_t ws_size,
                              hipStream_t stream) {
    const float* feat    = (const float*)d_in[0];
    const float* weights = (const float*)d_in[1];
    const float* w1      = (const float*)d_in[2];
    const float* b1      = (const float*)d_in[3];
    const float* w2      = (const float*)d_in[4];
    const float* b2      = (const float*)d_in[5];
    const float* gamma   = (const float*)d_in[6];
    const float* beta    = (const float*)d_in[7];
    float* out = (float*)d_out;

    float* sigw = (float*)d_ws;             // 64
    float* invn = sigw + 64;                // 57600
    float* tsum = invn + BB * TT * NN;      // 192*64 = 12288
    f16*   w1f  = (f16*)(tsum + BB * TT * DD);  // 4096 f16 (16B-aligned)
    f16*   w2f  = w1f + 4096;               // 4096 f16

    hipMemsetAsync(tsum, 0, (size_t)BB * TT * DD * sizeof(float), stream);
    k_prep<<<BB * TT * 5 + 1, 256, 0, stream>>>(feat, weights, w1, w2,
                                                sigw, invn, tsum, w1f, w2f);
    k_agg<<<NW * 5, 256, 0, stream>>>(feat, sigw, invn, tsum, out);
    k_ffn<<<(BB * T2C * NN) / 64, 256, 0, stream>>>(out, feat, w1f, w2f, b1, b2,
                                                    gamma, beta, out);
}